// Round 6
// baseline (36241.086 us; speedup 1.0000x reference)
//
#include <hip/hip_runtime.h>
#include <hip/hip_cooperative_groups.h>
#include <math.h>

namespace cg = cooperative_groups;

constexpr int kB = 64, kS = 24, kT = 96, kE = 256, kH = 512, kA = 512;
constexpr int NWG = 256, NTH = 512;
constexpr int GB = 16;  // batches per group (4 groups of 64 WGs)
constexpr int HC = 8;   // h-cols per WG
constexpr int GC = 32;  // gate cols per WG (4 gates x 8 h-cols)

// ws layout (floats)
constexpr int OFF_H   = 0;                          // 2*kB*kH word h (double buf)
constexpr int OFF_SH  = OFF_H + 2 * kB * kH;        // 2*kB*kH sent h (double buf)
constexpr int OFF_HS  = OFF_SH + 2 * kB * kH;       // kB*kT*kH word_hs
constexpr int OFF_Z   = OFF_HS + kB * kT * kH;      // kB*kT
constexpr int OFF_CTX = OFF_Z + kB * kT;            // kB*kH
constexpr int OFF_SHS = OFF_CTX + kB * kH;          // kB*kS*kH
constexpr int OFF_Z2  = OFF_SHS + kB * kS * kH;     // kB*kS
constexpr int OFF_FLG = (OFF_Z2 + kB * kS + 31) & ~31;  // 256 flags, 128B apart

__device__ __forceinline__ float sigmoidf(float x) { return 1.0f / (1.0f + expf(-x)); }
__device__ __forceinline__ float dot4(float4 a, float4 b) {
  return a.x * b.x + a.y * b.y + a.z * b.z + a.w * b.w;
}
// Coherent LLC access for cross-WG data (h, hs, ctx, sh, sent_hs, z, z2).
__device__ __forceinline__ float2 aload2(const float* p) {
  unsigned long long u = __hip_atomic_load((const unsigned long long*)p,
                                           __ATOMIC_RELAXED, __HIP_MEMORY_SCOPE_AGENT);
  union { unsigned long long u; float2 f; } cv; cv.u = u;
  return cv.f;
}
__device__ __forceinline__ float aload1(const float* p) {
  return __hip_atomic_load(p, __ATOMIC_RELAXED, __HIP_MEMORY_SCOPE_AGENT);
}
__device__ __forceinline__ void astore(float* p, float v) {
  __hip_atomic_store(p, v, __ATOMIC_RELAXED, __HIP_MEMORY_SCOPE_AGENT);
}
// LDS bank swizzle on 16B-chunk index within a 512-float row (128 chunks):
// read pattern (jj, u): kc = 16*jj + u -> kc^jj spreads the 8 jj-addresses
// across distinct 4-bank groups (conflict-free b128 broadcast reads).
__device__ __forceinline__ int swz(int kc) { return kc ^ ((kc >> 4) & 7); }

__global__ __launch_bounds__(NTH) void ha_kernel(
    const int* __restrict__ captions, const int* __restrict__ masks,
    const float* __restrict__ embed_W,
    const float* __restrict__ w_Wih, const float* __restrict__ w_Whh,
    const float* __restrict__ w_bih, const float* __restrict__ w_bhh,
    const float* __restrict__ s_Wih, const float* __restrict__ s_Whh,
    const float* __restrict__ s_bih, const float* __restrict__ s_bhh,
    const float* __restrict__ wa_Wk, const float* __restrict__ wa_Wv,
    const float* __restrict__ sa_Wk, const float* __restrict__ sa_Wv,
    float* __restrict__ out, float* __restrict__ ws) {
  cg::grid_group grid = cg::this_grid();
  const int g = blockIdx.x, tid = threadIdx.x;
  const int gb = g & 3, gm = g >> 2;   // group id (4), member id (64)
  const int B0 = GB * gb;              // first batch of group
  const int hc0 = HC * gm;             // first owned h-col
  // GEMV thread map: wave=cc (owns 4 gate cols), jj: 64-k slice, bp: 2 batches
  const int cc = tid >> 6, jj = (tid >> 3) & 7, bp = tid & 7;
  const int b0 = 2 * bp, b1 = b0 + 1;

  float* h_buf = ws + OFF_H;
  float* sh_buf = ws + OFF_SH;
  float* hs_buf = ws + OFF_HS;
  float* z_buf = ws + OFF_Z;
  float* ctx_ws = ws + OFF_CTX;
  float* sent_hs = ws + OFF_SHS;
  float* z2_buf = ws + OFF_Z2;
  unsigned* flags = (unsigned*)(ws + OFF_FLG);
  unsigned* myflag = &flags[(gb * 64 + gm) * 32];

  // LDS ~123 KB
  __shared__ __align__(16) float whh_s[GC][kH];     // 64 KB, swizzled chunks
  __shared__ float bias_s[GC];
  __shared__ __align__(16) float smem_u[GB * kH + GC * GB * 10];  // h_s | partial
  __shared__ float gates_s[GC][GB];
  __shared__ float c_s[HC][GB], hown_s[HC][GB], sc_s[HC][GB];
  __shared__ float soft_s[kT], red_s[96];

  float (*h_s)[kH] = reinterpret_cast<float (*)[kH]>(&smem_u[0]);
  float (*part)[GB][10] =
      reinterpret_cast<float (*)[GB][10]>(&smem_u[GB * kH]);
  float* attn_f = &smem_u[0];  // attention staging (12 x 516), aliases h_s

  auto grow = [&](int c) { return (c >> 3) * kH + hc0 + (c & 7); };

  // ---- init ----
  for (int idx = tid; idx < GC * kH; idx += NTH) {
    int c = idx >> 9, k = idx & (kH - 1);
    whh_s[c][swz(k >> 2) * 4 + (k & 3)] = w_Whh[(size_t)grow(c) * kH + k];
  }
  if (tid < GC) bias_s[tid] = w_bih[grow(tid)] + w_bhh[grow(tid)];
  if (tid < HC * GB) {
    c_s[tid >> 4][tid & 15] = 0.f;
    hown_s[tid >> 4][tid & 15] = 0.f;
    sc_s[tid >> 4][tid & 15] = 0.f;
  }
  {
    int idx = g * NTH + tid;  // 131072 == 2*(2*kB*kH)
    if (idx < 2 * kB * kH) h_buf[idx] = 0.f;
    else sh_buf[idx - 2 * kB * kH] = 0.f;
  }
  if (g == 0)
    for (int idx = tid; idx < NWG * 32; idx += NTH) flags[idx] = 0u;
  grid.sync();  // publish zeros + flags (only grid-wide sync in the kernel)

  // intra-group broadcast barrier (64 WGs)
  auto arrive = [&](unsigned nn) {
    __syncthreads();  // waves drain vmcnt before s_barrier -> data in LLC
    if (tid == 0)
      __hip_atomic_store(myflag, nn, __ATOMIC_RELAXED, __HIP_MEMORY_SCOPE_AGENT);
  };
  auto wait = [&](unsigned nn) {
    if (tid < 64) {
      while (__hip_atomic_load(&flags[(gb * 64 + tid) * 32], __ATOMIC_RELAXED,
                               __HIP_MEMORY_SCOPE_AGENT) < nn)
        __builtin_amdgcn_s_sleep(1);
    }
    __syncthreads();
  };
  // stage a [16][512] row-major global region into h_s (coalesced, swizzled)
  auto stage16 = [&](const float* src) {
#pragma unroll
    for (int r = 0; r < 8; ++r) {
      const int f = (r * 512 + tid) * 2;
      const int b = f >> 9, k = f & (kH - 1);
      float2 v = aload2(src + b * kH + k);
      *(float2*)&h_s[b][swz(k >> 2) * 4 + (k & 3)] = v;
    }
  };

  // x@Wih^T register partials (own 4 cols x 2 batches, jj's 32-e slice)
  float xp[4][2];
  auto prefetch = [&](int s2, int t2) {
    const int cap0 = captions[((B0 + b0) * kS + s2) * kT + t2];
    const int cap1 = captions[((B0 + b1) * kS + s2) * kT + t2];
    const float4* __restrict__ x0 = (const float4*)(embed_W + (size_t)cap0 * kE);
    const float4* __restrict__ x1 = (const float4*)(embed_W + (size_t)cap1 * kE);
#pragma unroll
    for (int d = 0; d < 4; ++d) { xp[d][0] = 0.f; xp[d][1] = 0.f; }
#pragma unroll 2
    for (int u = 0; u < 8; ++u) {
      const int ec = 8 * jj + u;
      const float4 xv0 = x0[ec], xv1 = x1[ec];
#pragma unroll
      for (int d = 0; d < 4; ++d) {
        const float4 w = *(const float4*)&w_Wih[(size_t)grow(4 * cc + d) * kE + 4 * ec];
        xp[d][0] += dot4(w, xv0);
        xp[d][1] += dot4(w, xv1);
      }
    }
  };
  // precomputed swizzled LDS offsets for this thread's 16 k-chunks
  int offs[16];
#pragma unroll
  for (int u = 0; u < 16; ++u) offs[u] = swz(16 * jj + u) * 4;

  prefetch(0, 0);
  unsigned n = 0;
  int gstep = 0;
  for (int s = 0; s < kS; ++s) {
    // ================= word LSTM: 96 steps =================
    for (int t = 0; t < kT; ++t, ++gstep) {
      const float* hcur = h_buf + (gstep & 1) * kB * kH;
      float* hnxt = h_buf + ((gstep + 1) & 1) * kB * kH;

      stage16(hcur + B0 * kH);
      __syncthreads();

      float acc[4][2];
#pragma unroll
      for (int d = 0; d < 4; ++d) { acc[d][0] = xp[d][0]; acc[d][1] = xp[d][1]; }
#pragma unroll 4
      for (int u = 0; u < 16; ++u) {
        const int off = offs[u];
        const float4 h0v = *(const float4*)&h_s[b0][off];
        const float4 h1v = *(const float4*)&h_s[b1][off];
#pragma unroll
        for (int d = 0; d < 4; ++d) {
          const float4 w = *(const float4*)&whh_s[4 * cc + d][off];
          acc[d][0] += dot4(w, h0v);
          acc[d][1] += dot4(w, h1v);
        }
      }
#pragma unroll
      for (int d = 0; d < 4; ++d) {
        part[4 * cc + d][b0][jj] = acc[d][0];
        part[4 * cc + d][b1][jj] = acc[d][1];
      }
      __syncthreads();
      // reduce over jj: thread (c,b)
      {
        const int c = tid >> 4, b = tid & 15;
        float sum = bias_s[c];
#pragma unroll
        for (int j = 0; j < 8; ++j) sum += part[c][b][j];
        gates_s[c][b] = sum;
      }
      __syncthreads();
      // nonlinearity + masked state update + publish (own 8 cols x 16 b)
      if (tid < HC * GB) {
        const int hcl = tid >> 4, b = tid & 15;
        const float gi = gates_s[hcl][b], gf = gates_s[8 + hcl][b];
        const float gg = gates_s[16 + hcl][b], go = gates_s[24 + hcl][b];
        const float cold = c_s[hcl][b];
        const float c2 = sigmoidf(gf) * cold + sigmoidf(gi) * tanhf(gg);
        const float h2 = sigmoidf(go) * tanhf(c2);
        const int m = masks[((B0 + b) * kS + s) * kT + t];
        const float cn = m ? c2 : cold;
        const float hn = m ? h2 : hown_s[hcl][b];
        c_s[hcl][b] = cn;
        hown_s[hcl][b] = hn;
        const int col = hc0 + hcl;
        astore(&hnxt[(B0 + b) * kH + col], hn);
        astore(&hs_buf[((B0 + b) * kT + t) * kH + col], m ? h2 : 0.f);
      }
      ++n;
      arrive(n);
      if (t < kT - 1) prefetch(s, t + 1);  // hidden in barrier window
      wait(n);
    }

    // ================= word attention: z[b,t] (group-local) =================
    {
      const int ab = gm >> 2, at0 = (gm & 3) * 24;
      const int bg = B0 + ab;
      for (int half = 0; half < 2; ++half) {
        const int tb = at0 + half * 12;
        for (int idx = tid; idx < 12 * 256; idx += NTH) {
          int pp = idx >> 8, hh2 = (idx & 255) * 2;
          float2 v = aload2(&hs_buf[((size_t)bg * kT + tb + pp) * kH + hh2]);
          *(float2*)&attn_f[pp * 516 + hh2] = v;
        }
        __syncthreads();
        const int aa = tid;  // NTH == kA
        float dacc[12];
#pragma unroll
        for (int p = 0; p < 12; ++p) dacc[p] = 0.f;
        const float4* __restrict__ wk = (const float4*)(wa_Wk + (size_t)aa * kH);
        for (int k = 0; k < kH / 4; ++k) {
          float4 w = wk[k];
#pragma unroll
          for (int p = 0; p < 12; ++p)
            dacc[p] += dot4(w, *(const float4*)&attn_f[p * 516 + k * 4]);
        }
        const float wv = wa_Wv[aa];
        const int lane = tid & 63, wid = tid >> 6;
#pragma unroll
        for (int p = 0; p < 12; ++p) {
          float v = wv * tanhf(dacc[p]);
          v += __shfl_down(v, 32); v += __shfl_down(v, 16); v += __shfl_down(v, 8);
          v += __shfl_down(v, 4);  v += __shfl_down(v, 2);  v += __shfl_down(v, 1);
          if (lane == 0) red_s[wid * 12 + p] = v;
        }
        __syncthreads();
        if (tid < 12) {
          float sum = 0.f;
#pragma unroll
          for (int w = 0; w < 8; ++w) sum += red_s[w * 12 + tid];
          astore(&z_buf[bg * kT + tb + tid], sum);
        }
        __syncthreads();
      }
    }
    ++n; arrive(n); wait(n);

    // ================= softmax over T + ctx (16 WGs of group) =================
    if (gm < GB) {
      const int b = B0 + gm;
      if (tid < kT) soft_s[tid] = aload1(&z_buf[b * kT + tid]);
      __syncthreads();
      float mx = -1e30f;
      for (int i = 0; i < kT; ++i) mx = fmaxf(mx, soft_s[i]);
      float den = 0.f;
      for (int i = 0; i < kT; ++i) den += expf(soft_s[i] - mx);
      __syncthreads();
      if (tid < kT) soft_s[tid] = expf(soft_s[tid] - mx) / den;
      __syncthreads();
      {
        const int h0 = tid;
        float a0 = 0.f, a1 = 0.f, a2 = 0.f, a3 = 0.f;
        for (int tt = 0; tt < kT; tt += 4) {
          a0 += soft_s[tt + 0] * aload1(&hs_buf[((size_t)b * kT + tt + 0) * kH + h0]);
          a1 += soft_s[tt + 1] * aload1(&hs_buf[((size_t)b * kT + tt + 1) * kH + h0]);
          a2 += soft_s[tt + 2] * aload1(&hs_buf[((size_t)b * kT + tt + 2) * kH + h0]);
          a3 += soft_s[tt + 3] * aload1(&hs_buf[((size_t)b * kT + tt + 3) * kH + h0]);
        }
        astore(&ctx_ws[b * kH + h0], (a0 + a1) + (a2 + a3));
      }
    }
    ++n; arrive(n); wait(n);

    // ================= sentence LSTM (two-pass GEMV, weights streamed) ========
    {
      float acc[4][2];
#pragma unroll
      for (int d = 0; d < 4; ++d) { acc[d][0] = 0.f; acc[d][1] = 0.f; }
      // pass A: x = ctx
      stage16(ctx_ws + B0 * kH);
      __syncthreads();
#pragma unroll 2
      for (int u = 0; u < 16; ++u) {
        const int off = offs[u];
        const float4 x0v = *(const float4*)&h_s[b0][off];
        const float4 x1v = *(const float4*)&h_s[b1][off];
        const int kf = 64 * jj + 4 * u;
#pragma unroll
        for (int d = 0; d < 4; ++d) {
          const float4 w = *(const float4*)&s_Wih[(size_t)grow(4 * cc + d) * kH + kf];
          acc[d][0] += dot4(w, x0v);
          acc[d][1] += dot4(w, x1v);
        }
      }
      __syncthreads();
      // pass B: h = sh
      stage16(sh_buf + (s & 1) * kB * kH + B0 * kH);
      __syncthreads();
#pragma unroll 2
      for (int u = 0; u < 16; ++u) {
        const int off = offs[u];
        const float4 h0v = *(const float4*)&h_s[b0][off];
        const float4 h1v = *(const float4*)&h_s[b1][off];
        const int kf = 64 * jj + 4 * u;
#pragma unroll
        for (int d = 0; d < 4; ++d) {
          const float4 w = *(const float4*)&s_Whh[(size_t)grow(4 * cc + d) * kH + kf];
          acc[d][0] += dot4(w, h0v);
          acc[d][1] += dot4(w, h1v);
        }
      }
#pragma unroll
      for (int d = 0; d < 4; ++d) {
        part[4 * cc + d][b0][jj] = acc[d][0];
        part[4 * cc + d][b1][jj] = acc[d][1];
      }
      __syncthreads();
      {
        const int c = tid >> 4, b = tid & 15;
        const int row = grow(c);
        float sum = s_bih[row] + s_bhh[row];
#pragma unroll
        for (int j = 0; j < 8; ++j) sum += part[c][b][j];
        gates_s[c][b] = sum;
      }
      __syncthreads();
      if (tid < HC * GB) {
        const int hcl = tid >> 4, b = tid & 15;
        const float gi = gates_s[hcl][b], gf = gates_s[8 + hcl][b];
        const float gg = gates_s[16 + hcl][b], go = gates_s[24 + hcl][b];
        const float c2 = sigmoidf(gf) * sc_s[hcl][b] + sigmoidf(gi) * tanhf(gg);
        const float h2 = sigmoidf(go) * tanhf(c2);
        sc_s[hcl][b] = c2;
        const int col = hc0 + hcl;
        astore(&sh_buf[((s + 1) & 1) * kB * kH + (B0 + b) * kH + col], h2);
        astore(&sent_hs[((B0 + b) * kS + s) * kH + col], h2);
      }
    }
    ++n; arrive(n);
    if (s < kS - 1) prefetch(s + 1, 0);
    wait(n);
  }

  // ================= final attention over S (group-local) =================
  {
    const int pair0 = gm * 6;  // 384 (b,s) pairs / 64 WGs
    for (int idx = tid; idx < 6 * 256; idx += NTH) {
      int pp = idx >> 8, hh2 = (idx & 255) * 2;
      const int pr = pair0 + pp;
      float2 v = aload2(&sent_hs[((size_t)(B0 + pr / kS) * kS + pr % kS) * kH + hh2]);
      *(float2*)&attn_f[pp * 516 + hh2] = v;
    }
    __syncthreads();
    const int aa = tid;
    float dacc[6];
#pragma unroll
    for (int p = 0; p < 6; ++p) dacc[p] = 0.f;
    const float4* __restrict__ wk = (const float4*)(sa_Wk + (size_t)aa * kH);
    for (int k = 0; k < kH / 4; ++k) {
      float4 w = wk[k];
#pragma unroll
      for (int p = 0; p < 6; ++p)
        dacc[p] += dot4(w, *(const float4*)&attn_f[p * 516 + k * 4]);
    }
    const float wv = sa_Wv[aa];
    const int lane = tid & 63, wid = tid >> 6;
#pragma unroll
    for (int p = 0; p < 6; ++p) {
      float v = wv * tanhf(dacc[p]);
      v += __shfl_down(v, 32); v += __shfl_down(v, 16); v += __shfl_down(v, 8);
      v += __shfl_down(v, 4);  v += __shfl_down(v, 2);  v += __shfl_down(v, 1);
      if (lane == 0) red_s[wid * 6 + p] = v;
    }
    __syncthreads();
    if (tid < 6) {
      float sum = 0.f;
#pragma unroll
      for (int w = 0; w < 8; ++w) sum += red_s[w * 6 + tid];
      astore(&z2_buf[B0 * kS + pair0 + tid], sum);
    }
  }
  ++n; arrive(n); wait(n);

  // ================= final softmax + outputs (16 WGs of group) =============
  if (gm < GB) {
    const int b = B0 + gm;
    if (tid < kS) soft_s[tid] = aload1(&z2_buf[b * kS + tid]);
    __syncthreads();
    float mx = -1e30f;
    for (int i = 0; i < kS; ++i) mx = fmaxf(mx, soft_s[i]);
    float den = 0.f;
    for (int i = 0; i < kS; ++i) den += expf(soft_s[i] - mx);
    __syncthreads();
    if (tid < kS) {
      float al = expf(soft_s[tid] - mx) / den;
      soft_s[tid] = al;
      out[kB * kH + b * kS + tid] = al;  // alpha
    }
    __syncthreads();
    {
      const int h0 = tid;
      float acc = 0.f;
      for (int s2 = 0; s2 < kS; ++s2)
        acc += soft_s[s2] * aload1(&sent_hs[((size_t)b * kS + s2) * kH + h0]);
      out[b * kH + h0] = acc;  // context
    }
  }
}

extern "C" void kernel_launch(void* const* d_in, const int* in_sizes, int n_in,
                              void* d_out, int out_size, void* d_ws, size_t ws_size,
                              hipStream_t stream) {
  (void)in_sizes; (void)n_in; (void)out_size; (void)ws_size;
  const int* captions = (const int*)d_in[0];
  const int* masks = (const int*)d_in[1];
  const float* embed_W = (const float*)d_in[2];
  const float* w_Wih = (const float*)d_in[3];
  const float* w_Whh = (const float*)d_in[4];
  const float* w_bih = (const float*)d_in[5];
  const float* w_bhh = (const float*)d_in[6];
  const float* s_Wih = (const float*)d_in[7];
  const float* s_Whh = (const float*)d_in[8];
  const float* s_bih = (const float*)d_in[9];
  const float* s_bhh = (const float*)d_in[10];
  const float* wa_Wk = (const float*)d_in[11];
  const float* wa_Wv = (const float*)d_in[12];
  const float* sa_Wk = (const float*)d_in[13];
  const float* sa_Wv = (const float*)d_in[14];
  float* out = (float*)d_out;
  float* ws = (float*)d_ws;

  void* args[] = {&captions, &masks, &embed_W, &w_Wih, &w_Whh, &w_bih, &w_bhh,
                  &s_Wih, &s_Whh, &s_bih, &s_bhh, &wa_Wk, &wa_Wv, &sa_Wk, &sa_Wv,
                  &out, &ws};
  hipLaunchCooperativeKernel((void*)ha_kernel, dim3(NWG), dim3(NTH), args, 0, stream);
}

// Round 7
// 32976.855 us; speedup vs baseline: 1.0990x; 1.0990x over previous
//
#include <hip/hip_runtime.h>
#include <hip/hip_cooperative_groups.h>
#include <math.h>

namespace cg = cooperative_groups;

constexpr int kB = 64, kS = 24, kT = 96, kE = 256, kH = 512, kA = 512;
constexpr int NWG = 256, NTH = 512;
constexpr int GB = 16;  // batches per group (4 groups of 64 WGs)
constexpr int HC = 8;   // h-cols per WG
constexpr int GC = 32;  // gate cols per WG
constexpr int HP = 516; // padded LDS row stride (floats)

// ws layout (floats)
constexpr int OFF_H   = 0;
constexpr int OFF_SH  = OFF_H + 2 * kB * kH;
constexpr int OFF_HS  = OFF_SH + 2 * kB * kH;
constexpr int OFF_Z   = OFF_HS + kB * kT * kH;
constexpr int OFF_CTX = OFF_Z + kB * kT;
constexpr int OFF_SHS = OFF_CTX + kB * kH;
constexpr int OFF_Z2  = OFF_SHS + kB * kS * kH;
constexpr int OFF_FLG = (OFF_Z2 + kB * kS + 31) & ~31;  // 256 flags + 8 done, 128B apart

__device__ __forceinline__ float sigmoidf(float x) { return 1.0f / (1.0f + expf(-x)); }
__device__ __forceinline__ float dot4(float4 a, float4 b) {
  return a.x * b.x + a.y * b.y + a.z * b.z + a.w * b.w;
}
__device__ __forceinline__ float2 aload2(const float* p) {
  unsigned long long u = __hip_atomic_load((const unsigned long long*)p,
                                           __ATOMIC_RELAXED, __HIP_MEMORY_SCOPE_AGENT);
  union { unsigned long long u; float2 f; } cv; cv.u = u;
  return cv.f;
}
__device__ __forceinline__ float aload1(const float* p) {
  return __hip_atomic_load(p, __ATOMIC_RELAXED, __HIP_MEMORY_SCOPE_AGENT);
}
__device__ __forceinline__ void astore(float* p, float v) {
  __hip_atomic_store(p, v, __ATOMIC_RELAXED, __HIP_MEMORY_SCOPE_AGENT);
}
__device__ __forceinline__ unsigned aloadu(const unsigned* p) {
  return __hip_atomic_load(p, __ATOMIC_RELAXED, __HIP_MEMORY_SCOPE_AGENT);
}
__device__ __forceinline__ void astoreu(unsigned* p, unsigned v) {
  __hip_atomic_store(p, v, __ATOMIC_RELAXED, __HIP_MEMORY_SCOPE_AGENT);
}

__global__ __launch_bounds__(NTH) void ha_kernel(
    const int* __restrict__ captions, const int* __restrict__ masks,
    const float* __restrict__ embed_W,
    const float* __restrict__ w_Wih, const float* __restrict__ w_Whh,
    const float* __restrict__ w_bih, const float* __restrict__ w_bhh,
    const float* __restrict__ s_Wih, const float* __restrict__ s_Whh,
    const float* __restrict__ s_bih, const float* __restrict__ s_bhh,
    const float* __restrict__ wa_Wk, const float* __restrict__ wa_Wv,
    const float* __restrict__ sa_Wk, const float* __restrict__ sa_Wv,
    float* __restrict__ out, float* __restrict__ ws) {
  cg::grid_group grid = cg::this_grid();
  const int g = blockIdx.x, tid = threadIdx.x;
  const int gb = g & 3, gm = g >> 2;   // group id (4), member id (64)
  const int B0 = GB * gb;
  const int hc0 = HC * gm;
  // GEMV map: wave jj = k-slice (64 k), lane = (cc: 4 cols each, bp: 2 batches)
  const int jj = tid >> 6;
  const int lane = tid & 63, cc = lane >> 3, bp = lane & 7;
  const int b0 = 2 * bp, b1 = b0 + 1;

  float* h_buf = ws + OFF_H;
  float* sh_buf = ws + OFF_SH;
  float* hs_buf = ws + OFF_HS;
  float* z_buf = ws + OFF_Z;
  float* ctx_ws = ws + OFF_CTX;
  float* sent_hs = ws + OFF_SHS;
  float* z2_buf = ws + OFF_Z2;
  unsigned* flags = (unsigned*)(ws + OFF_FLG);
  unsigned* myflag = &flags[(gb * 64 + gm) * 32];
  unsigned* donec = &flags[256 * 32 + gb * 32];

  // LDS ~121 KB
  __shared__ __align__(16) float whh_s[GC][HP];   // row r=d*8+cc: bank 4cc distinct
  __shared__ float bias_s[GC];
  __shared__ __align__(16) float smem_u[GB * HP + 8 * 576];  // h_s | part (aliased attn)
  __shared__ float gates_s[GC][GB];
  __shared__ float c_s[HC][GB], hown_s[HC][GB], sc_s[HC][GB];
  __shared__ float soft_s[kT], red_s[96];

  float (*h_s)[HP] = reinterpret_cast<float (*)[HP]>(&smem_u[0]);
  float* part_f = &smem_u[GB * HP];
  float* attn_f = &smem_u[0];  // 12 x 516 staging, aliases h_s

  auto grow = [&](int c) { return (c >> 3) * kH + hc0 + (c & 7); };

  // ---- init ----
  for (int idx = tid; idx < GC * kH; idx += NTH) {
    int r = idx >> 9, k = idx & (kH - 1);
    int c_log = 4 * (r & 7) + (r >> 3);
    whh_s[r][k] = w_Whh[(size_t)grow(c_log) * kH + k];
  }
  if (tid < GC) bias_s[tid] = w_bih[grow(tid)] + w_bhh[grow(tid)];
  if (tid < HC * GB) {
    c_s[tid >> 4][tid & 15] = 0.f;
    hown_s[tid >> 4][tid & 15] = 0.f;
    sc_s[tid >> 4][tid & 15] = 0.f;
  }
  {
    int idx = g * NTH + tid;
    if (idx < 2 * kB * kH) h_buf[idx] = 0.f;
    else sh_buf[idx - 2 * kB * kH] = 0.f;
  }
  if (g == 0)
    for (int idx = tid; idx < 264 * 32; idx += NTH) flags[idx] = 0u;
  grid.sync();

  // Leader barrier (per 64-WG group). Monotonic counters, relaxed stores.
  auto arrive = [&](unsigned nn) {
    __syncthreads();  // waves drain vmcnt before s_barrier -> data visible in LLC
    if (tid == 0) astoreu(myflag, nn);
  };
  auto wait = [&](unsigned nn) {
    if (gm == 0) {  // leader: 64 threads poll 64 member flags in parallel
      if (tid < 64) {
        while (aloadu(&flags[(gb * 64 + tid) * 32]) < nn)
          __builtin_amdgcn_s_sleep(1);
      }
      __syncthreads();
      if (tid == 0) astoreu(donec, nn);
    } else {  // member: single thread polls the group's done line
      if (tid == 0) {
        while (aloadu(donec) < nn) __builtin_amdgcn_s_sleep(3);
      }
    }
    __syncthreads();
  };

  // stage a [16][512] global region into h_s with per-batch chunk rotation:
  // element (b,k) -> chunk ((k>>2)+(b>>1)) & 127. GEMV read of batch pair
  // (2bp,2bp+1) at chunk 16jj+u uses offH = ((16jj+u+bp)&127)*4:
  // bank start = 4*((3bp + chunk) mod 8) -> distinct across bp, broadcast across cc.
  auto stage16 = [&](const float* src) {
#pragma unroll
    for (int r = 0; r < 8; ++r) {
      const int f = (r * 512 + tid) * 2;
      const int b = f >> 9, k = f & (kH - 1);
      float2 v = aload2(src + b * kH + k);
      const int ch = (((k >> 2) + (b >> 1)) & 127) * 4 + (k & 3);
      *(float2*)&h_s[b][ch] = v;
    }
  };

  // x@Wih^T register partials: cols 4cc+d, batches (b0,b1), E-chunks 8jj..8jj+7
  float xp[4][2];
  auto prefetch = [&](int s2, int t2) {
    const int cap0 = captions[((B0 + b0) * kS + s2) * kT + t2];
    const int cap1 = captions[((B0 + b1) * kS + s2) * kT + t2];
    const float4* __restrict__ x0 = (const float4*)(embed_W + (size_t)cap0 * kE);
    const float4* __restrict__ x1 = (const float4*)(embed_W + (size_t)cap1 * kE);
#pragma unroll
    for (int d = 0; d < 4; ++d) { xp[d][0] = 0.f; xp[d][1] = 0.f; }
#pragma unroll 2
    for (int u = 0; u < 8; ++u) {
      const int ec = 8 * jj + u;
      const float4 xv0 = x0[ec], xv1 = x1[ec];
#pragma unroll
      for (int d = 0; d < 4; ++d) {
        const float4 w = *(const float4*)&w_Wih[(size_t)grow(4 * cc + d) * kE + 4 * ec];
        xp[d][0] += dot4(w, xv0);
        xp[d][1] += dot4(w, xv1);
      }
    }
  };

  prefetch(0, 0);
  unsigned n = 0;
  int gstep = 0;
  for (int s = 0; s < kS; ++s) {
    // ================= word LSTM: 96 steps =================
    for (int t = 0; t < kT; ++t, ++gstep) {
      const float* hcur = h_buf + (gstep & 1) * kB * kH;
      float* hnxt = h_buf + ((gstep + 1) & 1) * kB * kH;

      stage16(hcur + B0 * kH);
      __syncthreads();

      float acc[4][2];
#pragma unroll
      for (int d = 0; d < 4; ++d) { acc[d][0] = xp[d][0]; acc[d][1] = xp[d][1]; }
#pragma unroll 4
      for (int u = 0; u < 16; ++u) {
        const int chunk = 16 * jj + u;
        const int offW = chunk * 4;
        const int offH = ((chunk + bp) & 127) * 4;
        const float4 h0v = *(const float4*)&h_s[b0][offH];
        const float4 h1v = *(const float4*)&h_s[b1][offH];
#pragma unroll
        for (int d = 0; d < 4; ++d) {
          const float4 w = *(const float4*)&whh_s[d * 8 + cc][offW];
          acc[d][0] += dot4(w, h0v);
          acc[d][1] += dot4(w, h1v);
        }
      }
      // partials: stride-9 lane layout (2 lanes/bank, free)
#pragma unroll
      for (int d = 0; d < 4; ++d) {
        part_f[jj * 576 + lane * 9 + d * 2 + 0] = acc[d][0];
        part_f[jj * 576 + lane * 9 + d * 2 + 1] = acc[d][1];
      }
      __syncthreads();
      // reduce over jj: thread (c_log, b)
      {
        const int c = tid >> 4, b = tid & 15;
        const int lp = (c >> 2) * 8 + (b >> 1), sl = (c & 3) * 2 + (b & 1);
        float sum = bias_s[c];
#pragma unroll
        for (int j = 0; j < 8; ++j) sum += part_f[j * 576 + lp * 9 + sl];
        gates_s[c][b] = sum;
      }
      __syncthreads();
      if (tid < HC * GB) {
        const int hcl = tid >> 4, b = tid & 15;
        const float gi = gates_s[hcl][b], gf = gates_s[8 + hcl][b];
        const float gg = gates_s[16 + hcl][b], go = gates_s[24 + hcl][b];
        const float cold = c_s[hcl][b];
        const float c2 = sigmoidf(gf) * cold + sigmoidf(gi) * tanhf(gg);
        const float h2 = sigmoidf(go) * tanhf(c2);
        const int m = masks[((B0 + b) * kS + s) * kT + t];
        const float cn = m ? c2 : cold;
        const float hn = m ? h2 : hown_s[hcl][b];
        c_s[hcl][b] = cn;
        hown_s[hcl][b] = hn;
        const int col = hc0 + hcl;
        astore(&hnxt[(B0 + b) * kH + col], hn);
        astore(&hs_buf[((B0 + b) * kT + t) * kH + col], m ? h2 : 0.f);
      }
      ++n;
      arrive(n);
      if (t < kT - 1) prefetch(s, t + 1);
      wait(n);
    }

    // ================= word attention: z[b,t] (group-local) =================
    {
      const int ab = gm >> 2, at0 = (gm & 3) * 24;
      const int bg = B0 + ab;
      for (int half = 0; half < 2; ++half) {
        const int tb = at0 + half * 12;
        for (int idx = tid; idx < 12 * 256; idx += NTH) {
          int pp = idx >> 8, hh2 = (idx & 255) * 2;
          float2 v = aload2(&hs_buf[((size_t)bg * kT + tb + pp) * kH + hh2]);
          *(float2*)&attn_f[pp * HP + hh2] = v;
        }
        __syncthreads();
        const int aa = tid;  // NTH == kA
        float dacc[12];
#pragma unroll
        for (int p = 0; p < 12; ++p) dacc[p] = 0.f;
        const float4* __restrict__ wk = (const float4*)(wa_Wk + (size_t)aa * kH);
        for (int k = 0; k < kH / 4; ++k) {
          float4 w = wk[k];
#pragma unroll
          for (int p = 0; p < 12; ++p)
            dacc[p] += dot4(w, *(const float4*)&attn_f[p * HP + k * 4]);
        }
        const float wv = wa_Wv[aa];
        const int ln = tid & 63, wid = tid >> 6;
#pragma unroll
        for (int p = 0; p < 12; ++p) {
          float v = wv * tanhf(dacc[p]);
          v += __shfl_down(v, 32); v += __shfl_down(v, 16); v += __shfl_down(v, 8);
          v += __shfl_down(v, 4);  v += __shfl_down(v, 2);  v += __shfl_down(v, 1);
          if (ln == 0) red_s[wid * 12 + p] = v;
        }
        __syncthreads();
        if (tid < 12) {
          float sum = 0.f;
#pragma unroll
          for (int w = 0; w < 8; ++w) sum += red_s[w * 12 + tid];
          astore(&z_buf[bg * kT + tb + tid], sum);
        }
        __syncthreads();
      }
    }
    ++n; arrive(n); wait(n);

    // ================= softmax over T + ctx =================
    if (gm < GB) {
      const int b = B0 + gm;
      if (tid < kT) soft_s[tid] = aload1(&z_buf[b * kT + tid]);
      __syncthreads();
      float mx = -1e30f;
      for (int i = 0; i < kT; ++i) mx = fmaxf(mx, soft_s[i]);
      float den = 0.f;
      for (int i = 0; i < kT; ++i) den += expf(soft_s[i] - mx);
      __syncthreads();
      if (tid < kT) soft_s[tid] = expf(soft_s[tid] - mx) / den;
      __syncthreads();
      {
        const int h0 = tid;
        float a0 = 0.f, a1 = 0.f, a2 = 0.f, a3 = 0.f;
        for (int tt = 0; tt < kT; tt += 4) {
          a0 += soft_s[tt + 0] * aload1(&hs_buf[((size_t)b * kT + tt + 0) * kH + h0]);
          a1 += soft_s[tt + 1] * aload1(&hs_buf[((size_t)b * kT + tt + 1) * kH + h0]);
          a2 += soft_s[tt + 2] * aload1(&hs_buf[((size_t)b * kT + tt + 2) * kH + h0]);
          a3 += soft_s[tt + 3] * aload1(&hs_buf[((size_t)b * kT + tt + 3) * kH + h0]);
        }
        astore(&ctx_ws[b * kH + h0], (a0 + a1) + (a2 + a3));
      }
    }
    ++n; arrive(n); wait(n);

    // ================= sentence LSTM (two-pass GEMV) =================
    {
      float acc[4][2];
#pragma unroll
      for (int d = 0; d < 4; ++d) { acc[d][0] = 0.f; acc[d][1] = 0.f; }
      stage16(ctx_ws + B0 * kH);  // pass A: x = ctx
      __syncthreads();
#pragma unroll 2
      for (int u = 0; u < 16; ++u) {
        const int chunk = 16 * jj + u;
        const int offH = ((chunk + bp) & 127) * 4;
        const float4 x0v = *(const float4*)&h_s[b0][offH];
        const float4 x1v = *(const float4*)&h_s[b1][offH];
#pragma unroll
        for (int d = 0; d < 4; ++d) {
          const float4 w = *(const float4*)&s_Wih[(size_t)grow(4 * cc + d) * kH + chunk * 4];
          acc[d][0] += dot4(w, x0v);
          acc[d][1] += dot4(w, x1v);
        }
      }
      __syncthreads();
      stage16(sh_buf + (s & 1) * kB * kH + B0 * kH);  // pass B: h = sh
      __syncthreads();
#pragma unroll 2
      for (int u = 0; u < 16; ++u) {
        const int chunk = 16 * jj + u;
        const int offH = ((chunk + bp) & 127) * 4;
        const float4 h0v = *(const float4*)&h_s[b0][offH];
        const float4 h1v = *(const float4*)&h_s[b1][offH];
#pragma unroll
        for (int d = 0; d < 4; ++d) {
          const float4 w = *(const float4*)&s_Whh[(size_t)grow(4 * cc + d) * kH + chunk * 4];
          acc[d][0] += dot4(w, h0v);
          acc[d][1] += dot4(w, h1v);
        }
      }
#pragma unroll
      for (int d = 0; d < 4; ++d) {
        part_f[jj * 576 + lane * 9 + d * 2 + 0] = acc[d][0];
        part_f[jj * 576 + lane * 9 + d * 2 + 1] = acc[d][1];
      }
      __syncthreads();
      {
        const int c = tid >> 4, b = tid & 15;
        const int lp = (c >> 2) * 8 + (b >> 1), sl = (c & 3) * 2 + (b & 1);
        const int row = grow(c);
        float sum = s_bih[row] + s_bhh[row];
#pragma unroll
        for (int j = 0; j < 8; ++j) sum += part_f[j * 576 + lp * 9 + sl];
        gates_s[c][b] = sum;
      }
      __syncthreads();
      if (tid < HC * GB) {
        const int hcl = tid >> 4, b = tid & 15;
        const float gi = gates_s[hcl][b], gf = gates_s[8 + hcl][b];
        const float gg = gates_s[16 + hcl][b], go = gates_s[24 + hcl][b];
        const float c2 = sigmoidf(gf) * sc_s[hcl][b] + sigmoidf(gi) * tanhf(gg);
        const float h2 = sigmoidf(go) * tanhf(c2);
        sc_s[hcl][b] = c2;
        const int col = hc0 + hcl;
        astore(&sh_buf[((s + 1) & 1) * kB * kH + (B0 + b) * kH + col], h2);
        astore(&sent_hs[((B0 + b) * kS + s) * kH + col], h2);
      }
    }
    ++n; arrive(n);
    if (s < kS - 1) prefetch(s + 1, 0);
    wait(n);
  }

  // ================= final attention over S (group-local) =================
  {
    const int pair0 = gm * 6;
    for (int idx = tid; idx < 6 * 256; idx += NTH) {
      int pp = idx >> 8, hh2 = (idx & 255) * 2;
      const int pr = pair0 + pp;
      float2 v = aload2(&sent_hs[((size_t)(B0 + pr / kS) * kS + pr % kS) * kH + hh2]);
      *(float2*)&attn_f[pp * HP + hh2] = v;
    }
    __syncthreads();
    const int aa = tid;
    float dacc[6];
#pragma unroll
    for (int p = 0; p < 6; ++p) dacc[p] = 0.f;
    const float4* __restrict__ wk = (const float4*)(sa_Wk + (size_t)aa * kH);
    for (int k = 0; k < kH / 4; ++k) {
      float4 w = wk[k];
#pragma unroll
      for (int p = 0; p < 6; ++p)
        dacc[p] += dot4(w, *(const float4*)&attn_f[p * HP + k * 4]);
    }
    const float wv = sa_Wv[aa];
    const int ln = tid & 63, wid = tid >> 6;
#pragma unroll
    for (int p = 0; p < 6; ++p) {
      float v = wv * tanhf(dacc[p]);
      v += __shfl_down(v, 32); v += __shfl_down(v, 16); v += __shfl_down(v, 8);
      v += __shfl_down(v, 4);  v += __shfl_down(v, 2);  v += __shfl_down(v, 1);
      if (ln == 0) red_s[wid * 6 + p] = v;
    }
    __syncthreads();
    if (tid < 6) {
      float sum = 0.f;
#pragma unroll
      for (int w = 0; w < 8; ++w) sum += red_s[w * 6 + tid];
      astore(&z2_buf[B0 * kS + pair0 + tid], sum);
    }
  }
  ++n; arrive(n); wait(n);

  // ================= final softmax + outputs =================
  if (gm < GB) {
    const int b = B0 + gm;
    if (tid < kS) soft_s[tid] = aload1(&z2_buf[b * kS + tid]);
    __syncthreads();
    float mx = -1e30f;
    for (int i = 0; i < kS; ++i) mx = fmaxf(mx, soft_s[i]);
    float den = 0.f;
    for (int i = 0; i < kS; ++i) den += expf(soft_s[i] - mx);
    __syncthreads();
    if (tid < kS) {
      float al = expf(soft_s[tid] - mx) / den;
      soft_s[tid] = al;
      out[kB * kH + b * kS + tid] = al;  // alpha
    }
    __syncthreads();
    {
      const int h0 = tid;
      float acc = 0.f;
      for (int s2 = 0; s2 < kS; ++s2)
        acc += soft_s[s2] * aload1(&sent_hs[((size_t)b * kS + s2) * kH + h0]);
      out[b * kH + h0] = acc;  // context
    }
  }
}

extern "C" void kernel_launch(void* const* d_in, const int* in_sizes, int n_in,
                              void* d_out, int out_size, void* d_ws, size_t ws_size,
                              hipStream_t stream) {
  (void)in_sizes; (void)n_in; (void)out_size; (void)ws_size;
  const int* captions = (const int*)d_in[0];
  const int* masks = (const int*)d_in[1];
  const float* embed_W = (const float*)d_in[2];
  const float* w_Wih = (const float*)d_in[3];
  const float* w_Whh = (const float*)d_in[4];
  const float* w_bih = (const float*)d_in[5];
  const float* w_bhh = (const float*)d_in[6];
  const float* s_Wih = (const float*)d_in[7];
  const float* s_Whh = (const float*)d_in[8];
  const float* s_bih = (const float*)d_in[9];
  const float* s_bhh = (const float*)d_in[10];
  const float* wa_Wk = (const float*)d_in[11];
  const float* wa_Wv = (const float*)d_in[12];
  const float* sa_Wk = (const float*)d_in[13];
  const float* sa_Wv = (const float*)d_in[14];
  float* out = (float*)d_out;
  float* ws = (float*)d_ws;

  void* args[] = {&captions, &masks, &embed_W, &w_Wih, &w_Whh, &w_bih, &w_bhh,
                  &s_Wih, &s_Whh, &s_bih, &s_bhh, &wa_Wk, &wa_Wv, &sa_Wk, &sa_Wv,
                  &out, &ws};
  hipLaunchCooperativeKernel((void*)ha_kernel, dim3(NWG), dim3(NTH), args, 0, stream);
}